// Round 8
// baseline (53.596 us; speedup 1.0000x reference)
//
#include <hip/hip_runtime.h>

// Problem geometry (fixed by the reference file).
constexpr int B = 16;
constexpr int V = 16384;                 // variants per batch
constexpr int G = 20000;                 // genes
constexpr int D = 64;                    // embedding dim
constexpr int NCELLS = B * G;            // 320,000 output cells
constexpr int NROWS  = B * V;            // 262,144 variant rows
constexpr int OVF_MAX = 16384;
constexpr long long OUT_N = (long long)NCELLS * D;   // 20,480,000 floats

// Native vector type accepted by __builtin_nontemporal_load/store.
typedef float f32x4 __attribute__((ext_vector_type(4)));

// ---------------------------- header+spill layout ----------------------------
// ws layout (u32 units):
//   [0, 4*NCELLS)                       headers: {count, r0, r1, r2} per cell
//   [OVF_HDR]                           overflow counter
//   [OVF_LIST, OVF_LIST+2*OVF_MAX)     overflow (cell,row) pairs
//   [SPILL_OFF, SPILL_OFF+NCELLS*SCAP) spill rows (rows 3..3+SCAP-1 per cell)
constexpr int HDR_WORDS = 4 * NCELLS;
constexpr int OVF_HDR   = HDR_WORDS;
constexpr int OVF_LIST  = HDR_WORDS + 1;
constexpr int SPILL_OFF = HDR_WORDS + 1 + 2 * OVF_MAX;

__global__ void ga_zero(uint4* __restrict__ ws4, unsigned int* __restrict__ ws) {
  int stride = gridDim.x * blockDim.x;
  for (int i = blockIdx.x * blockDim.x + threadIdx.x; i < HDR_WORDS / 4; i += stride)
    ws4[i] = make_uint4(0u, 0u, 0u, 0u);
  if (blockIdx.x == 0 && threadIdx.x == 0) ws[OVF_HDR] = 0u;
}

__global__ void ga_build(const int* __restrict__ gene_ids,
                         const int* __restrict__ mask,
                         unsigned int* __restrict__ ws, int scap) {
  int r = blockIdx.x * blockDim.x + threadIdx.x;   // global variant row
  if (r >= NROWS) return;
  if (!mask[r]) return;
  int cell = (r >> 14) * G + gene_ids[r];          // r>>14 == batch
  unsigned int pos = atomicAdd(&ws[cell * 4], 1u);
  if (pos < 3u) {
    ws[cell * 4 + 1 + pos] = (unsigned int)r;
  } else if (pos < 3u + (unsigned int)scap) {
    ws[SPILL_OFF + (size_t)cell * scap + (pos - 3u)] = (unsigned int)r;
  } else {
    unsigned int o = atomicAdd(&ws[OVF_HDR], 1u);
    if (o < (unsigned int)OVF_MAX) {
      ws[OVF_LIST + 2 * o + 0] = (unsigned int)cell;
      ws[OVF_LIST + 2 * o + 1] = (unsigned int)r;
    }
  }
}

__device__ __forceinline__ void fmax4(f32x4& a, f32x4 v) {
  a.x = fmaxf(a.x, v.x);
  a.y = fmaxf(a.y, v.y);
  a.z = fmaxf(a.z, v.z);
  a.w = fmaxf(a.w, v.w);
}

// XCD-partitioned gather. Block j runs on XCD (j&7) [round-robin dispatch],
// and is assigned batch = (j&7) + 8*(second half). All emb reads of a block
// therefore target ONE batch's 4 MB slice -> per-XCD read working set is
// 8 MB (2 batches) vs 64 MB before, so the random row reads hit XCD-local L2
// instead of crossing the fabric to L3 every time.
// Within a block: 16 groups x 16 lanes; group gi handles cells
// local*128 + gi + k*16 (k<CPT) of its batch; 16 lanes split D.
// Zero-branch common path (c<=3): rows clamped to r0; max(a,a)=a.
constexpr int CPT = 8;
constexpr int CELLS_PER_BLOCK  = (256 / 16) * CPT;                 // 128
constexpr int BLOCKS_PER_BATCH = (G + CELLS_PER_BLOCK - 1) / CELLS_PER_BLOCK; // 157
constexpr int GATHER_BLOCKS    = BLOCKS_PER_BATCH * B;             // 2512

__global__ void ga_gather(const f32x4* __restrict__ emb4,
                          const uint4* __restrict__ hdr,
                          const unsigned int* __restrict__ spill,
                          f32x4* __restrict__ out4, int scap) {
  int j   = blockIdx.x;
  int xcd = j & 7;
  int jj  = j >> 3;                                // 0..313
  int half  = (jj >= BLOCKS_PER_BATCH) ? 1 : 0;
  int local = jj - half * BLOCKS_PER_BATCH;        // 0..156
  int batch = xcd + 8 * half;

  int gi  = threadIdx.x >> 4;                      // group 0..15
  int sub = threadIdx.x & 15;
  int cidx0 = local * CELLS_PER_BLOCK + gi;        // cell-in-batch for k=0

  uint4 h[CPT];
#pragma unroll
  for (int k = 0; k < CPT; ++k) {
    int cidx = cidx0 + k * 16;
    int cc   = cidx < G ? cidx : G - 1;            // clamp (tail block only)
    h[k] = hdr[(size_t)batch * G + cc];
  }

  f32x4 v0[CPT], v1[CPT], v2[CPT];
#pragma unroll
  for (int k = 0; k < CPT; ++k) {
    unsigned int c  = h[k].x;
    unsigned int r0 = c ? h[k].y : (unsigned int)(batch * V);  // empty -> batch's row 0 (L2-hot)
    unsigned int r1 = (c >= 2u) ? h[k].z : r0;     // clamp -> same line as v0
    unsigned int r2 = (c >= 3u) ? h[k].w : r0;
    v0[k] = emb4[(size_t)r0 * 16 + sub];
    v1[k] = emb4[(size_t)r1 * 16 + sub];
    v2[k] = emb4[(size_t)r2 * 16 + sub];
  }

#pragma unroll
  for (int k = 0; k < CPT; ++k) {
    int cidx = cidx0 + k * 16;
    if (cidx >= G) continue;                       // tail of last chunk only
    size_t cell = (size_t)batch * G + cidx;
    unsigned int c = h[k].x;
    f32x4 acc = v0[k];
    fmax4(acc, v1[k]);                             // duplicate -> no-op
    fmax4(acc, v2[k]);
    if (c > 3u) {                                  // rare spill path (~1%)
      int n1 = (int)c - 3; if (n1 > scap) n1 = scap;
      const unsigned int* sp = spill + cell * scap;
      for (int jx = 0; jx < n1; ++jx)
        fmax4(acc, emb4[(size_t)sp[jx] * 16 + sub]);
    }
    acc.x = c ? acc.x : 0.f;                       // cndmask, no branch
    acc.y = c ? acc.y : 0.f;
    acc.z = c ? acc.z : 0.f;
    acc.w = c ? acc.w : 0.f;
    __builtin_nontemporal_store(acc, &out4[cell * 16 + sub]);
  }
}

__device__ __forceinline__ void atomic_max_float(float* addr, float val) {
  unsigned int* ua = (unsigned int*)addr;
  unsigned int old = *ua;
  while (__uint_as_float(old) < val) {
    unsigned int assumed = old;
    old = atomicCAS(ua, assumed, __float_as_uint(val));
    if (old == assumed) break;
  }
}

// Drain overflow entries (expected: none — P(cell count > 3+scap) ~ 1e-10).
__global__ void ga_ovf(const f32x4* __restrict__ emb4,
                       const unsigned int* __restrict__ ws,
                       float* __restrict__ out) {
  unsigned int nov = ws[OVF_HDR];
  if (nov > (unsigned int)OVF_MAX) nov = OVF_MAX;
  int total = (int)nov * 16;
  int stride = gridDim.x * blockDim.x;
  for (int u = blockIdx.x * blockDim.x + threadIdx.x; u < total; u += stride) {
    int e = u >> 4, sub = u & 15;
    unsigned int cell = ws[OVF_LIST + 2 * e + 0];
    unsigned int row  = ws[OVF_LIST + 2 * e + 1];
    f32x4 v = emb4[(size_t)row * 16 + sub];
    float* o = out + (size_t)cell * 64 + sub * 4;
    atomic_max_float(o + 0, v.x);
    atomic_max_float(o + 1, v.y);
    atomic_max_float(o + 2, v.z);
    atomic_max_float(o + 3, v.w);
  }
}

// ------------------------- legacy atomic path (ws too small) -----------------
__device__ __forceinline__ unsigned int enc_f32(float f) {
  unsigned int u = __float_as_uint(f);
  return (u & 0x80000000u) ? ~u : (u | 0x80000000u);
}
__device__ __forceinline__ float dec_f32(unsigned int e) {
  unsigned int u = (e & 0x80000000u) ? (e ^ 0x80000000u) : ~e;
  return __uint_as_float(u);
}

__global__ void ga_init(uint4* __restrict__ out4, int n4) {
  int stride = gridDim.x * blockDim.x;
  for (int i = blockIdx.x * blockDim.x + threadIdx.x; i < n4; i += stride)
    out4[i] = make_uint4(0u, 0u, 0u, 0u);
}

__global__ void ga_scatter(const float4* __restrict__ emb4,
                           const int* __restrict__ gene_ids,
                           const int* __restrict__ mask,
                           unsigned int* __restrict__ out) {
  int tid = blockIdx.x * blockDim.x + threadIdx.x;
  int v  = tid >> 4;
  int dq = tid & 15;
  if (!mask[v]) return;
  int g = gene_ids[v];
  int b = v >> 14;
  float4 e = emb4[tid];
  int base = (b * G + g) * D + (dq << 2);
  atomicMax(out + base + 0, enc_f32(e.x));
  atomicMax(out + base + 1, enc_f32(e.y));
  atomicMax(out + base + 2, enc_f32(e.z));
  atomicMax(out + base + 3, enc_f32(e.w));
}

__global__ void ga_finalize(uint4* __restrict__ io4, int n4) {
  int stride = gridDim.x * blockDim.x;
  for (int i = blockIdx.x * blockDim.x + threadIdx.x; i < n4; i += stride) {
    uint4 e = io4[i];
    float4 f;
    f.x = e.x ? dec_f32(e.x) : 0.0f;
    f.y = e.y ? dec_f32(e.y) : 0.0f;
    f.z = e.z ? dec_f32(e.z) : 0.0f;
    f.w = e.w ? dec_f32(e.w) : 0.0f;
    *reinterpret_cast<float4*>(io4 + i) = f;
  }
}

// -----------------------------------------------------------------------------
extern "C" void kernel_launch(void* const* d_in, const int* in_sizes, int n_in,
                              void* d_out, int out_size, void* d_ws, size_t ws_size,
                              hipStream_t stream) {
  const float4* emb4     = (const float4*)d_in[0];   // [B,V,D] f32
  const int*    gene_ids = (const int*)d_in[1];      // [B,V]
  const int*    mask     = (const int*)d_in[2];      // [B,V]

  long long ws_u32 = (long long)(ws_size / 4);
  long long avail  = ws_u32 - (long long)SPILL_OFF;
  int scap = (int)(avail > 0 ? avail / NCELLS : -1);
  if (scap > 13) scap = 13;

  if (scap >= 0) {
    unsigned int* ws = (unsigned int*)d_ws;
    ga_zero<<<1024, 256, 0, stream>>>((uint4*)d_ws, ws);
    ga_build<<<NROWS / 256, 256, 0, stream>>>(gene_ids, mask, ws, scap);
    ga_gather<<<GATHER_BLOCKS, 256, 0, stream>>>(
        (const f32x4*)emb4, (const uint4*)d_ws, ws + SPILL_OFF,
        (f32x4*)d_out, scap);
    ga_ovf<<<64, 256, 0, stream>>>((const f32x4*)emb4, ws, (float*)d_out);
  } else {
    // Fallback: direct atomic scatter-max (round-1 passing version).
    unsigned int* out_u = (unsigned int*)d_out;
    const int n4 = (int)(OUT_N / 4);
    ga_init<<<2048, 256, 0, stream>>>((uint4*)d_out, n4);
    ga_scatter<<<(NROWS * 16) / 256, 256, 0, stream>>>(emb4, gene_ids, mask, out_u);
    ga_finalize<<<2048, 256, 0, stream>>>((uint4*)d_out, n4);
  }
}